// Round 3
// baseline (2005.865 us; speedup 1.0000x reference)
//
#include <hip/hip_runtime.h>
#include <math.h>

#define D_MODEL 2048
#define NHEADS  16
#define DHEAD   128
#define SEQ     2048
#define BATCH   2
#define ROWS    (BATCH * SEQ)        // 4096
#define D_FF    (4 * D_MODEL)        // 8192

typedef __attribute__((ext_vector_type(8))) short bf16x8;   // 8 bf16 in 4 VGPRs
typedef __attribute__((ext_vector_type(4))) float f32x4;

// round-to-nearest-even fp32 -> bf16 (bit pattern)
__device__ __forceinline__ unsigned short f2bf(float f) {
    unsigned int u = __float_as_uint(f);
    u += 0x7fffu + ((u >> 16) & 1u);
    return (unsigned short)(u >> 16);
}

// ---------------- block reduce (sum or max) over 256 threads ----------------
__device__ __forceinline__ float block_reduce(float v, int is_max) {
    __shared__ float tmp[4];
    #pragma unroll
    for (int o = 32; o > 0; o >>= 1) {
        float other = __shfl_down(v, o, 64);
        v = is_max ? fmaxf(v, other) : (v + other);
    }
    __syncthreads();
    if ((threadIdx.x & 63) == 0) tmp[threadIdx.x >> 6] = v;
    __syncthreads();
    float r = is_max ? fmaxf(fmaxf(tmp[0], tmp[1]), fmaxf(tmp[2], tmp[3]))
                     : (tmp[0] + tmp[1] + tmp[2] + tmp[3]);
    return r;
}

// ---------------- fp32 -> bf16 cast (n4 = n/4 float4 groups) ----------------
__global__ __launch_bounds__(256)
void castbf_kernel(const float* __restrict__ in, unsigned short* __restrict__ out, int n4)
{
    int i = blockIdx.x * 256 + threadIdx.x;
    if (i < n4) {
        float4 v = ((const float4*)in)[i];
        ushort4 o;
        o.x = f2bf(v.x); o.y = f2bf(v.y); o.z = f2bf(v.z); o.w = f2bf(v.w);
        ((ushort4*)out)[i] = o;
    }
}

// ---------------- LayerNorm: fp32 in, bf16 out ------------------------------
__global__ __launch_bounds__(256)
void ln_kernel(const float* __restrict__ x, const float* __restrict__ g,
               const float* __restrict__ b, unsigned short* __restrict__ y)
{
    __shared__ float row[D_MODEL];
    const long r = blockIdx.x;
    const float4* xr = (const float4*)(x + r * D_MODEL);
    float s = 0.f;
    for (int i = threadIdx.x; i < D_MODEL / 4; i += 256) {
        float4 v = xr[i];
        ((float4*)row)[i] = v;
        s += v.x + v.y + v.z + v.w;
    }
    s = block_reduce(s, 0);
    const float mean = s * (1.f / D_MODEL);
    float vs = 0.f;
    for (int i = threadIdx.x; i < D_MODEL / 4; i += 256) {
        float4 v = ((const float4*)row)[i];
        float dx = v.x - mean; vs += dx * dx;
        dx = v.y - mean; vs += dx * dx;
        dx = v.z - mean; vs += dx * dx;
        dx = v.w - mean; vs += dx * dx;
    }
    vs = block_reduce(vs, 0);
    const float inv = rsqrtf(vs * (1.f / D_MODEL) + 1e-5f);
    const float4* g4 = (const float4*)g;
    const float4* b4 = (const float4*)b;
    for (int i = threadIdx.x; i < D_MODEL / 4; i += 256) {
        float4 v = ((const float4*)row)[i];
        float4 gg = g4[i], bb = b4[i];
        ushort4 o;
        o.x = f2bf((v.x - mean) * inv * gg.x + bb.x);
        o.y = f2bf((v.y - mean) * inv * gg.y + bb.y);
        o.z = f2bf((v.z - mean) * inv * gg.z + bb.z);
        o.w = f2bf((v.w - mean) * inv * gg.w + bb.w);
        *(ushort4*)(y + r * D_MODEL + i * 4) = o;
    }
}

// ---------------- Softmax (in place, fp32): one block per row ---------------
__global__ __launch_bounds__(256)
void softmax_kernel(float* __restrict__ sc)
{
    __shared__ float row[SEQ];
    float* p = sc + (long)blockIdx.x * SEQ;
    float m = -1e30f;
    for (int i = threadIdx.x; i < SEQ / 4; i += 256) {
        float4 v = ((const float4*)p)[i];
        ((float4*)row)[i] = v;
        m = fmaxf(m, fmaxf(fmaxf(v.x, v.y), fmaxf(v.z, v.w)));
    }
    m = block_reduce(m, 1);
    float sum = 0.f;
    for (int i = threadIdx.x; i < SEQ; i += 256) {
        float e = expf(row[i] - m);
        row[i] = e;
        sum += e;
    }
    sum = block_reduce(sum, 0);
    const float inv = 1.f / sum;
    for (int i = threadIdx.x; i < SEQ / 4; i += 256) {
        float4 v = ((const float4*)p)[i];
        v.x = row[i * 4 + 0] * inv; v.y = row[i * 4 + 1] * inv;
        v.z = row[i * 4 + 2] * inv; v.w = row[i * 4 + 3] * inv;
        ((float4*)p)[i] = v;
    }
}

// ---------------- MFMA bf16 GEMM --------------------------------------------
// C[m,n] = relu?( scale * sum_k A[m,k]*B[n,k] + bias + resid[m,n] )
// A: bf16 [M,K] (or fp32 if AF32, converted during staging). B: bf16 [N,K].
// Batched over blockIdx.z (zb = z/nh, zh = z%nh); strides in ELEMENTS.
// Tile 128x128, BK=64, 256 threads = 4 waves, each wave a 64x64 sub-tile of
// 4x4 mfma_f32_16x16x32_bf16 fragments.
// Staging:
//  - !AF32: global_load_lds width=16, LINEAR [128][64] LDS (m97 structure;
//           T2 swizzle is null at 2-phase per m230/m252).
//  - AF32:  per-lane loads + in-register fp32->bf16 + XOR-swizzled ds_write
//           (global_load_lds cannot convert dtypes).
// Requires M%128==0, N%128==0, K%64==0.
constexpr int BK = 64;

// swizzled reg-staging (AF32 only): chunk (16B) index XOR row&7
__device__ __forceinline__ void stage_tile_f32(const float* g, int ld,
                                               unsigned short* lds, int t)
{
    const int row = t >> 1;        // 0..127
    const int half = t & 1;        // k-half: chunks half*4 .. half*4+3
    char* lbase = (char*)lds + row * 128;
    const float* gr = g + (size_t)row * ld + half * 32;
    #pragma unroll
    for (int c4 = 0; c4 < 4; ++c4) {
        float4 f0 = *(const float4*)(gr + c4 * 8);
        float4 f1 = *(const float4*)(gr + c4 * 8 + 4);
        bf16x8 v;
        v[0] = (short)f2bf(f0.x); v[1] = (short)f2bf(f0.y);
        v[2] = (short)f2bf(f0.z); v[3] = (short)f2bf(f0.w);
        v[4] = (short)f2bf(f1.x); v[5] = (short)f2bf(f1.y);
        v[6] = (short)f2bf(f1.z); v[7] = (short)f2bf(f1.w);
        const int cs = (half * 4 + c4) ^ (row & 7);
        *(bf16x8*)(lbase + cs * 16) = v;
    }
}

// bf16 reg-staging with swizzle (AF32 kernel's B operand)
__device__ __forceinline__ void stage_tile_bf(const unsigned short* g, int ld,
                                              unsigned short* lds, int t)
{
    const int row = t >> 1;
    const int half = t & 1;
    char* lbase = (char*)lds + row * 128;
    const unsigned short* gr = g + (size_t)row * ld + half * 32;
    #pragma unroll
    for (int c4 = 0; c4 < 4; ++c4) {
        bf16x8 v = *(const bf16x8*)(gr + c4 * 8);
        const int cs = (half * 4 + c4) ^ (row & 7);
        *(bf16x8*)(lbase + cs * 16) = v;
    }
}

// direct global->LDS DMA, linear [128][64] bf16 layout.
// Wave w covers rows [w*32, w*32+32): 4 issues of 8 rows (1 KB each).
// Lane l -> row base+ (l>>3), 16B chunk (l&7). LDS dst is wave-uniform base.
__device__ __forceinline__ void stage_lds(const unsigned short* gbase, int ld,
                                          unsigned short* lds, int wid, int lane)
{
    const int l8 = lane >> 3, c8 = lane & 7;
    #pragma unroll
    for (int i = 0; i < 4; ++i) {
        const int rowb = wid * 32 + i * 8;
        const unsigned short* src = gbase + (size_t)(rowb + l8) * ld + c8 * 8;
        unsigned short* dst = lds + rowb * 64;
        __builtin_amdgcn_global_load_lds(
            (const __attribute__((address_space(1))) unsigned int*)src,
            (__attribute__((address_space(3))) unsigned int*)dst, 16, 0, 0);
    }
}

template<bool AF32, bool OUTBF>
__global__ __launch_bounds__(256)
void gemm_mfma(const void* __restrict__ Av, int lda,
               const unsigned short* __restrict__ B, int ldb,
               const float* __restrict__ bias, int biasM,
               const float* __restrict__ resid,
               void* __restrict__ Cv, int ldc,
               int Kdim, float scale, int relu,
               long sAb, long sAh, long sBb, long sBh, long sCb, long sCh,
               int nh)
{
    __shared__ unsigned short As[128 * BK];   // 16 KB
    __shared__ unsigned short Bs[128 * BK];   // 16 KB

    const int z  = blockIdx.z;
    const int zb = z / nh, zh = z % nh;
    const long aoff = zb * sAb + zh * sAh;
    const float*          Af = (const float*)Av + (AF32 ? aoff : 0);
    const unsigned short* Ah = (const unsigned short*)Av + (AF32 ? 0 : aoff);
    B += zb * sBb + zh * sBh;
    const long coff = zb * sCb + zh * sCh;
    float*          Cf = (float*)Cv + coff;
    unsigned short* Ch = (unsigned short*)Cv + coff;

    const int bm = blockIdx.y * 128;
    const int bn = blockIdx.x * 128;
    const int t  = threadIdx.x;
    const int lane = t & 63;
    const int wid  = t >> 6;
    const int wr = wid >> 1, wc = wid & 1;     // wave -> 64x64 sub-tile
    const int li = lane & 15;                  // fragment row-lane
    const int g  = lane >> 4;                  // k-group 0..3

    f32x4 acc[4][4];
    #pragma unroll
    for (int i = 0; i < 4; ++i)
        #pragma unroll
        for (int j = 0; j < 4; ++j) acc[i][j] = (f32x4){0.f, 0.f, 0.f, 0.f};

    // LDS byte offsets per fragment row (swizzled iff AF32 reg-staged path)
    int aoffs[4], boffs[4];
    #pragma unroll
    for (int m = 0; m < 4; ++m) {
        const int ra = wr * 64 + m * 16 + li;
        const int rb = wc * 64 + m * 16 + li;
        if (AF32) {
            aoffs[m] = ra * 128 + ((g ^ (ra & 7)) << 4);
            boffs[m] = rb * 128 + ((g ^ (rb & 7)) << 4);
        } else {
            aoffs[m] = ra * 128 + (g << 4);
            boffs[m] = rb * 128 + (g << 4);
        }
    }

    for (int k0 = 0; k0 < Kdim; k0 += BK) {
        if (AF32) {
            stage_tile_f32(Af + (size_t)bm * lda + k0, lda, As, t);
            stage_tile_bf (B  + (size_t)bn * ldb + k0, ldb, Bs, t);
        } else {
            stage_lds(Ah + (size_t)bm * lda + k0, lda, As, wid, lane);
            stage_lds(B  + (size_t)bn * ldb + k0, ldb, Bs, wid, lane);
        }
        __syncthreads();
        #pragma unroll
        for (int kk = 0; kk < 2; ++kk) {       // two K=32 MFMA slabs per tile
            const int kb = kk * 64;            // chunk idx +4 -> byte +64 (bit-disjoint)
            bf16x8 a[4], b[4];
            #pragma unroll
            for (int m = 0; m < 4; ++m) {
                a[m] = *(const bf16x8*)((const char*)As + (aoffs[m] ^ kb));
                b[m] = *(const bf16x8*)((const char*)Bs + (boffs[m] ^ kb));
            }
            #pragma unroll
            for (int m = 0; m < 4; ++m)
                #pragma unroll
                for (int n = 0; n < 4; ++n)
                    acc[m][n] = __builtin_amdgcn_mfma_f32_16x16x32_bf16(
                                    a[m], b[n], acc[m][n], 0, 0, 0);
        }
        __syncthreads();
    }

    // epilogue: C/D layout col = lane&15, row = (lane>>4)*4 + reg   [verified]
    const int g4 = g * 4;
    #pragma unroll
    for (int m = 0; m < 4; ++m) {
        #pragma unroll
        for (int n = 0; n < 4; ++n) {
            const int c = bn + wc * 64 + n * 16 + li;
            #pragma unroll
            for (int r = 0; r < 4; ++r) {
                const long R = bm + wr * 64 + m * 16 + g4 + r;
                float v = acc[m][n][r] * scale;
                if (bias)  v += biasM ? bias[R] : bias[c];
                if (resid) v += resid[R * (long)ldc + c];
                if (relu)  v = fmaxf(v, 0.f);
                if (OUTBF) Ch[R * (long)ldc + c] = f2bf(v);
                else       Cf[R * (long)ldc + c] = v;
            }
        }
    }
}

// ---------------------------------------------------------------------------
extern "C" void kernel_launch(void* const* d_in, const int* in_sizes, int n_in,
                              void* d_out, int out_size, void* d_ws, size_t ws_size,
                              hipStream_t stream)
{
    const float* x    = (const float*)d_in[0];
    const float* Wq   = (const float*)d_in[1];
    const float* bq   = (const float*)d_in[2];
    const float* Wk   = (const float*)d_in[3];
    const float* bk   = (const float*)d_in[4];
    const float* Wv   = (const float*)d_in[5];
    const float* bv   = (const float*)d_in[6];
    const float* Wo   = (const float*)d_in[7];
    const float* bo   = (const float*)d_in[8];
    const float* ln1g = (const float*)d_in[9];
    const float* ln1b = (const float*)d_in[10];
    const float* W1   = (const float*)d_in[11];
    const float* b1   = (const float*)d_in[12];
    const float* W2   = (const float*)d_in[13];
    const float* b2   = (const float*)d_in[14];
    const float* ln2g = (const float*)d_in[15];
    const float* ln2b = (const float*)d_in[16];

    const long XN = (long)ROWS * D_MODEL;      // 8,388,608
    float* out_x     = (float*)d_out;
    float* out_score = out_x + XN;             // [2][16][2048][2048] fp32

    // ---- workspace carve-up (bytes; total = exactly 256 MiB) ----
    char* w = (char*)d_ws;
    unsigned short* Qb   = (unsigned short*)(w);                    // 16 MiB
    unsigned short* Kb   = (unsigned short*)(w + (16u << 20));      // 16 MiB
    unsigned short* Vtb  = (unsigned short*)(w + (32u << 20));      // 16 MiB
    unsigned short* xlnb = (unsigned short*)(w + (48u << 20));      // 16 MiB
    unsigned short* hb   = (unsigned short*)(w + (64u << 20));      // 64 MiB
    float*          x1   = (float*)         (w + (128u << 20));     // 32 MiB
    unsigned short* Wqb  = (unsigned short*)(w + (160u << 20));     // 8 MiB
    unsigned short* Wkb  = (unsigned short*)(w + (168u << 20));     // 8 MiB
    unsigned short* Wvb  = (unsigned short*)(w + (176u << 20));     // 8 MiB
    unsigned short* Wob  = (unsigned short*)(w + (184u << 20));     // 8 MiB
    unsigned short* W1b  = (unsigned short*)(w + (192u << 20));     // 32 MiB
    unsigned short* W2b  = (unsigned short*)(w + (224u << 20));     // 32 MiB
    unsigned short* Ohb   = xlnb;   // xln dead after QKV/Vt gemms
    unsigned short* xln2b = Kb;     // K dead after scores gemm

    const dim3 blk(256);
    const float one = 1.f;
    const float qk_scale = 0.08838834764831843f;   // 1/sqrt(128)
    const long Z4M = (long)SEQ * D_MODEL;          // 4,194,304
    const long ZSC = (long)SEQ * SEQ;              // 4,194,304
    const long ZOH = (long)SEQ * DHEAD;            // 262,144

    // 0) weights -> bf16 (every call; no persistent state allowed)
    const int nW = D_MODEL * D_MODEL / 4, nF = D_FF * D_MODEL / 4;
    hipLaunchKernelGGL(castbf_kernel, dim3(nW / 256), blk, 0, stream, Wq, Wqb, nW);
    hipLaunchKernelGGL(castbf_kernel, dim3(nW / 256), blk, 0, stream, Wk, Wkb, nW);
    hipLaunchKernelGGL(castbf_kernel, dim3(nW / 256), blk, 0, stream, Wv, Wvb, nW);
    hipLaunchKernelGGL(castbf_kernel, dim3(nW / 256), blk, 0, stream, Wo, Wob, nW);
    hipLaunchKernelGGL(castbf_kernel, dim3(nF / 256), blk, 0, stream, W1, W1b, nF);
    hipLaunchKernelGGL(castbf_kernel, dim3(nF / 256), blk, 0, stream, W2, W2b, nF);

    // 1) LN1 -> bf16
    hipLaunchKernelGGL(ln_kernel, dim3(ROWS), blk, 0, stream, x, ln1g, ln1b, xlnb);

    // 2) Q = xln@Wq^T+bq, K = xln@Wk^T+bk  (bf16 out)
    hipLaunchKernelGGL((gemm_mfma<false, true>), dim3(D_MODEL / 128, ROWS / 128, 1), blk, 0, stream,
                       xlnb, D_MODEL, Wqb, D_MODEL, bq, 0, nullptr, Qb, D_MODEL,
                       D_MODEL, one, 0, 0L, 0L, 0L, 0L, 0L, 0L, 1);
    hipLaunchKernelGGL((gemm_mfma<false, true>), dim3(D_MODEL / 128, ROWS / 128, 1), blk, 0, stream,
                       xlnb, D_MODEL, Wkb, D_MODEL, bk, 0, nullptr, Kb, D_MODEL,
                       D_MODEL, one, 0, 0L, 0L, 0L, 0L, 0L, 0L, 1);
    // 2c) V^T per batch: Vt[b][dout][s] = sum_k Wv[dout,k]*xln[b][s][k] + bv[dout]
    hipLaunchKernelGGL((gemm_mfma<false, true>), dim3(SEQ / 128, D_MODEL / 128, BATCH), blk, 0, stream,
                       Wvb, D_MODEL, xlnb, D_MODEL, bv, 1, nullptr, Vtb, SEQ,
                       D_MODEL, one, 0, 0L, 0L, Z4M, 0L, Z4M, 0L, 1);

    // 3) scores = Q_h @ K_h^T * qk_scale  (fp32, into d_out score region)
    hipLaunchKernelGGL((gemm_mfma<false, false>), dim3(SEQ / 128, SEQ / 128, BATCH * NHEADS), blk, 0, stream,
                       Qb, D_MODEL, Kb, D_MODEL, nullptr, 0, nullptr, out_score, SEQ,
                       DHEAD, qk_scale, 0,
                       Z4M, (long)DHEAD, Z4M, (long)DHEAD, (long)NHEADS * ZSC, ZSC, NHEADS);

    // 4) softmax in place (fp32)
    hipLaunchKernelGGL(softmax_kernel, dim3(BATCH * NHEADS * SEQ), blk, 0, stream, out_score);

    // 5) Oh[b][h][s][d] = P @ V_h   (A = P fp32 converted in staging, B = Vt)
    hipLaunchKernelGGL((gemm_mfma<true, true>), dim3(DHEAD / 128, SEQ / 128, BATCH * NHEADS), blk, 0, stream,
                       out_score, SEQ, Vtb, SEQ, nullptr, 0, nullptr, Ohb, DHEAD,
                       SEQ, one, 0,
                       (long)NHEADS * ZSC, ZSC, Z4M, (long)DHEAD * SEQ,
                       (long)NHEADS * ZOH, ZOH, NHEADS);

    // 6) x1 = x + Oh_flat @ Wo^T + bo   (fp32 out)
    hipLaunchKernelGGL((gemm_mfma<false, false>), dim3(D_MODEL / 128, ROWS / 128, 1), blk, 0, stream,
                       Ohb, D_MODEL, Wob, D_MODEL, bo, 0, x, x1, D_MODEL,
                       D_MODEL, one, 0, 0L, 0L, 0L, 0L, 0L, 0L, 1);

    // 7) LN2 -> bf16
    hipLaunchKernelGGL(ln_kernel, dim3(ROWS), blk, 0, stream, x1, ln2g, ln2b, xln2b);

    // 8) h = relu(xln2 @ W1^T + b1)  (bf16 out)
    hipLaunchKernelGGL((gemm_mfma<false, true>), dim3(D_FF / 128, ROWS / 128, 1), blk, 0, stream,
                       xln2b, D_MODEL, W1b, D_MODEL, b1, 0, nullptr, hb, D_FF,
                       D_MODEL, one, 1, 0L, 0L, 0L, 0L, 0L, 0L, 1);

    // 9) out = x1 + h @ W2^T + b2  (fp32 out into d_out)
    hipLaunchKernelGGL((gemm_mfma<false, false>), dim3(D_MODEL / 128, ROWS / 128, 1), blk, 0, stream,
                       hb, D_FF, W2b, D_FF, b2, 0, x1, out_x, D_MODEL,
                       D_FF, one, 0, 0L, 0L, 0L, 0L, 0L, 0L, 1);
}

// Round 5
// 1969.220 us; speedup vs baseline: 1.0186x; 1.0186x over previous
//
#include <hip/hip_runtime.h>
#include <math.h>

#define D_MODEL 2048
#define NHEADS  16
#define DHEAD   128
#define SEQ     2048
#define BATCH   2
#define ROWS    (BATCH * SEQ)        // 4096
#define D_FF    (4 * D_MODEL)        // 8192

typedef __attribute__((ext_vector_type(8))) short bf16x8;   // 8 bf16 in 4 VGPRs
typedef __attribute__((ext_vector_type(4))) float f32x4;

// round-to-nearest-even fp32 -> bf16 (bit pattern)
__device__ __forceinline__ unsigned short f2bf(float f) {
    unsigned int u = __float_as_uint(f);
    u += 0x7fffu + ((u >> 16) & 1u);
    return (unsigned short)(u >> 16);
}

// ---------------- block reduce (sum or max) over 256 threads ----------------
__device__ __forceinline__ float block_reduce(float v, int is_max) {
    __shared__ float tmp[4];
    #pragma unroll
    for (int o = 32; o > 0; o >>= 1) {
        float other = __shfl_down(v, o, 64);
        v = is_max ? fmaxf(v, other) : (v + other);
    }
    __syncthreads();
    if ((threadIdx.x & 63) == 0) tmp[threadIdx.x >> 6] = v;
    __syncthreads();
    float r = is_max ? fmaxf(fmaxf(tmp[0], tmp[1]), fmaxf(tmp[2], tmp[3]))
                     : (tmp[0] + tmp[1] + tmp[2] + tmp[3]);
    return r;
}

// ---------------- fp32 -> bf16 cast (n4 = n/4 float4 groups) ----------------
__global__ __launch_bounds__(256)
void castbf_kernel(const float* __restrict__ in, unsigned short* __restrict__ out, int n4)
{
    int i = blockIdx.x * 256 + threadIdx.x;
    if (i < n4) {
        float4 v = ((const float4*)in)[i];
        ushort4 o;
        o.x = f2bf(v.x); o.y = f2bf(v.y); o.z = f2bf(v.z); o.w = f2bf(v.w);
        ((ushort4*)out)[i] = o;
    }
}

// ---------------- LayerNorm: fp32 in, bf16 out ------------------------------
__global__ __launch_bounds__(256)
void ln_kernel(const float* __restrict__ x, const float* __restrict__ g,
               const float* __restrict__ b, unsigned short* __restrict__ y)
{
    __shared__ float row[D_MODEL];
    const long r = blockIdx.x;
    const float4* xr = (const float4*)(x + r * D_MODEL);
    float s = 0.f;
    for (int i = threadIdx.x; i < D_MODEL / 4; i += 256) {
        float4 v = xr[i];
        ((float4*)row)[i] = v;
        s += v.x + v.y + v.z + v.w;
    }
    s = block_reduce(s, 0);
    const float mean = s * (1.f / D_MODEL);
    float vs = 0.f;
    for (int i = threadIdx.x; i < D_MODEL / 4; i += 256) {
        float4 v = ((const float4*)row)[i];
        float dx = v.x - mean; vs += dx * dx;
        dx = v.y - mean; vs += dx * dx;
        dx = v.z - mean; vs += dx * dx;
        dx = v.w - mean; vs += dx * dx;
    }
    vs = block_reduce(vs, 0);
    const float inv = rsqrtf(vs * (1.f / D_MODEL) + 1e-5f);
    const float4* g4 = (const float4*)g;
    const float4* b4 = (const float4*)b;
    for (int i = threadIdx.x; i < D_MODEL / 4; i += 256) {
        float4 v = ((const float4*)row)[i];
        float4 gg = g4[i], bb = b4[i];
        ushort4 o;
        o.x = f2bf((v.x - mean) * inv * gg.x + bb.x);
        o.y = f2bf((v.y - mean) * inv * gg.y + bb.y);
        o.z = f2bf((v.z - mean) * inv * gg.z + bb.z);
        o.w = f2bf((v.w - mean) * inv * gg.w + bb.w);
        *(ushort4*)(y + r * D_MODEL + i * 4) = o;
    }
}

// ---------------- Softmax in place + bf16 copy: one block per row -----------
__global__ __launch_bounds__(256)
void softmax_kernel(float* __restrict__ sc, unsigned short* __restrict__ pb)
{
    __shared__ float row[SEQ];
    float* p = sc + (long)blockIdx.x * SEQ;
    unsigned short* pbf = pb + (long)blockIdx.x * SEQ;
    float m = -1e30f;
    for (int i = threadIdx.x; i < SEQ / 4; i += 256) {
        float4 v = ((const float4*)p)[i];
        ((float4*)row)[i] = v;
        m = fmaxf(m, fmaxf(fmaxf(v.x, v.y), fmaxf(v.z, v.w)));
    }
    m = block_reduce(m, 1);
    float sum = 0.f;
    for (int i = threadIdx.x; i < SEQ; i += 256) {
        float e = expf(row[i] - m);
        row[i] = e;
        sum += e;
    }
    sum = block_reduce(sum, 0);
    const float inv = 1.f / sum;
    for (int i = threadIdx.x; i < SEQ / 4; i += 256) {
        float4 v = ((const float4*)row)[i];
        v.x *= inv; v.y *= inv; v.z *= inv; v.w *= inv;
        ((float4*)p)[i] = v;
        ushort4 o;
        o.x = f2bf(v.x); o.y = f2bf(v.y); o.z = f2bf(v.z); o.w = f2bf(v.w);
        ((ushort4*)pbf)[i] = o;
    }
}

// ---------------- MFMA bf16 GEMM --------------------------------------------
// C[m,n] = relu?( scale * sum_k A[m,k]*B[n,k] + bias + resid[m,n] )
// A: bf16 [M,K]. B: bf16 [N,K]. Batched over blockIdx.z (zb=z/nh, zh=z%nh).
// Tile 128x128, BK=64, 4 waves x (64x64 of 4x4 16x16x32 frags).
// Staging: global_load_lds width=16, LINEAR [128][64] LDS (m97 structure).
// Epilogue: acc -> swizzled LDS (reuse staging smem, 2 passes of 64x128 fp32)
// -> coalesced 16B stores; bias/resid applied at readback (coalesced reads).
// Requires M%128==0, N%128==0, K%64==0.
constexpr int BK = 64;

// direct global->LDS DMA, linear [128][64] bf16 layout.
// Wave w covers rows [w*32, w*32+32): 4 issues of 8 rows (1 KB each).
__device__ __forceinline__ void stage_lds(const unsigned short* gbase, int ld,
                                          unsigned short* lds, int wid, int lane)
{
    const int l8 = lane >> 3, c8 = lane & 7;
    #pragma unroll
    for (int i = 0; i < 4; ++i) {
        const int rowb = wid * 32 + i * 8;
        const unsigned short* src = gbase + (size_t)(rowb + l8) * ld + c8 * 8;
        unsigned short* dst = lds + rowb * 64;
        __builtin_amdgcn_global_load_lds(
            (const __attribute__((address_space(1))) unsigned int*)src,
            (__attribute__((address_space(3))) unsigned int*)dst, 16, 0, 0);
    }
}

template<bool OUTBF>
__global__ __launch_bounds__(256)
void gemm_mfma(const unsigned short* __restrict__ A, int lda,
               const unsigned short* __restrict__ B, int ldb,
               const float* __restrict__ bias, int biasM,
               const float* __restrict__ resid,
               void* __restrict__ Cv, int ldc,
               int Kdim, float scale, int relu,
               long sAb, long sAh, long sBb, long sBh, long sCb, long sCh,
               int nh)
{
    __shared__ __align__(16) char smem[32768];     // staging (2x16KB) / epilogue scratch
    unsigned short* As = (unsigned short*)smem;
    unsigned short* Bs = As + 128 * BK;

    const int z  = blockIdx.z;
    const int zb = z / nh, zh = z % nh;
    A += zb * sAb + zh * sAh;
    B += zb * sBb + zh * sBh;
    const long coff = zb * sCb + zh * sCh;
    float*          Cf = (float*)Cv + coff;
    unsigned short* Ch = (unsigned short*)Cv + coff;

    const int bm = blockIdx.y * 128;
    const int bn = blockIdx.x * 128;
    const int t  = threadIdx.x;
    const int lane = t & 63;
    const int wid  = t >> 6;
    const int wr = wid >> 1, wc = wid & 1;     // wave -> 64x64 sub-tile
    const int li = lane & 15;
    const int g  = lane >> 4;                  // k-group 0..3

    f32x4 acc[4][4];
    #pragma unroll
    for (int i = 0; i < 4; ++i)
        #pragma unroll
        for (int j = 0; j < 4; ++j) acc[i][j] = (f32x4){0.f, 0.f, 0.f, 0.f};

    int aoffs[4], boffs[4];
    #pragma unroll
    for (int m = 0; m < 4; ++m) {
        const int ra = wr * 64 + m * 16 + li;
        const int rb = wc * 64 + m * 16 + li;
        aoffs[m] = ra * 128 + (g << 4);
        boffs[m] = rb * 128 + (g << 4);
    }

    for (int k0 = 0; k0 < Kdim; k0 += BK) {
        stage_lds(A + (size_t)bm * lda + k0, lda, As, wid, lane);
        stage_lds(B + (size_t)bn * ldb + k0, ldb, Bs, wid, lane);
        __syncthreads();
        #pragma unroll
        for (int kk = 0; kk < 2; ++kk) {       // two K=32 MFMA slabs per tile
            const int kb = kk * 64;            // chunk idx +4 -> byte +64 (bit-disjoint)
            bf16x8 a[4], b[4];
            #pragma unroll
            for (int m = 0; m < 4; ++m) {
                a[m] = *(const bf16x8*)((const char*)As + (aoffs[m] ^ kb));
                b[m] = *(const bf16x8*)((const char*)Bs + (boffs[m] ^ kb));
            }
            #pragma unroll
            for (int m = 0; m < 4; ++m)
                #pragma unroll
                for (int n = 0; n < 4; ++n)
                    acc[m][n] = __builtin_amdgcn_mfma_f32_16x16x32_bf16(
                                    a[m], b[n], acc[m][n], 0, 0, 0);
        }
        __syncthreads();
    }

    // ---- epilogue via LDS roundtrip: 2 passes of 64 rows x 128 cols fp32 ----
    // MFMA C layout: col = lane&15, row = (lane>>4)*4 + reg  [HW-verified].
    // Pass p handles global rows {wr*64 + p*32 .. +32}; XOR-swizzle (chunk ^=
    // lrow&7) makes scalar writes 2-way (free) and b128 readback balanced.
    float* epi = (float*)smem;
    const int g4 = g * 4;
    const int lrow_r = t >> 2, q = t & 3;      // readback mapping
    #pragma unroll
    for (int p = 0; p < 2; ++p) {
        __syncthreads();
        #pragma unroll
        for (int mm = 0; mm < 2; ++mm) {
            const int m = 2 * p + mm;
            #pragma unroll
            for (int n = 0; n < 4; ++n) {
                const int col = wc * 64 + n * 16 + li;
                #pragma unroll
                for (int r = 0; r < 4; ++r) {
                    const int lrow = wr * 32 + mm * 16 + g4 + r;
                    const int byteoff = lrow * 512 + ((((col >> 2) ^ (lrow & 7)) << 4)) + (col & 3) * 4;
                    *(float*)((char*)epi + byteoff) = acc[m][n][r];
                }
            }
        }
        __syncthreads();
        const long grow = bm + (lrow_r >> 5) * 64 + p * 32 + (lrow_r & 31);
        const int col0 = bn + q * 32;
        float v[32];
        #pragma unroll
        for (int i = 0; i < 8; ++i) {
            const int byteoff = lrow_r * 512 + ((((q * 8 + i) ^ (lrow_r & 7)) << 4));
            *(f32x4*)&v[i * 4] = *(const f32x4*)((const char*)epi + byteoff);
        }
        #pragma unroll
        for (int i = 0; i < 32; ++i) v[i] *= scale;
        if (bias) {
            if (biasM) {
                const float bm_ = bias[grow];
                #pragma unroll
                for (int i = 0; i < 32; ++i) v[i] += bm_;
            } else {
                #pragma unroll
                for (int i = 0; i < 8; ++i) {
                    f32x4 bb = *(const f32x4*)(bias + col0 + i * 4);
                    v[i * 4 + 0] += bb[0]; v[i * 4 + 1] += bb[1];
                    v[i * 4 + 2] += bb[2]; v[i * 4 + 3] += bb[3];
                }
            }
        }
        if (resid) {
            const float* rr = resid + grow * (long)ldc + col0;
            #pragma unroll
            for (int i = 0; i < 8; ++i) {
                f32x4 r4 = *(const f32x4*)(rr + i * 4);
                v[i * 4 + 0] += r4[0]; v[i * 4 + 1] += r4[1];
                v[i * 4 + 2] += r4[2]; v[i * 4 + 3] += r4[3];
            }
        }
        if (relu) {
            #pragma unroll
            for (int i = 0; i < 32; ++i) v[i] = fmaxf(v[i], 0.f);
        }
        if (OUTBF) {
            unsigned short* cp = Ch + grow * (long)ldc + col0;
            #pragma unroll
            for (int i = 0; i < 4; ++i) {
                bf16x8 o;
                #pragma unroll
                for (int j = 0; j < 8; ++j) o[j] = (short)f2bf(v[i * 8 + j]);
                *(bf16x8*)(cp + i * 8) = o;
            }
        } else {
            float* cp = Cf + grow * (long)ldc + col0;
            #pragma unroll
            for (int i = 0; i < 8; ++i)
                *(f32x4*)(cp + i * 4) = *(const f32x4*)&v[i * 4];
        }
    }
}

// ---------------------------------------------------------------------------
extern "C" void kernel_launch(void* const* d_in, const int* in_sizes, int n_in,
                              void* d_out, int out_size, void* d_ws, size_t ws_size,
                              hipStream_t stream)
{
    const float* x    = (const float*)d_in[0];
    const float* Wq   = (const float*)d_in[1];
    const float* bq   = (const float*)d_in[2];
    const float* Wk   = (const float*)d_in[3];
    const float* bk   = (const float*)d_in[4];
    const float* Wv   = (const float*)d_in[5];
    const float* bv   = (const float*)d_in[6];
    const float* Wo   = (const float*)d_in[7];
    const float* bo   = (const float*)d_in[8];
    const float* ln1g = (const float*)d_in[9];
    const float* ln1b = (const float*)d_in[10];
    const float* W1   = (const float*)d_in[11];
    const float* b1   = (const float*)d_in[12];
    const float* W2   = (const float*)d_in[13];
    const float* b2   = (const float*)d_in[14];
    const float* ln2g = (const float*)d_in[15];
    const float* ln2b = (const float*)d_in[16];

    const long XN = (long)ROWS * D_MODEL;      // 8,388,608
    float* out_x     = (float*)d_out;
    float* out_score = out_x + XN;             // [2][16][2048][2048] fp32

    // ---- workspace carve-up (bytes; 512 MiB used, d_ws is ~2.2 GiB) ----
    char* w = (char*)d_ws;
    unsigned short* Qb   = (unsigned short*)(w);                    // 16 MiB
    unsigned short* Kb   = (unsigned short*)(w + (16u << 20));      // 16 MiB
    unsigned short* Vtb  = (unsigned short*)(w + (32u << 20));      // 16 MiB
    unsigned short* xlnb = (unsigned short*)(w + (48u << 20));      // 16 MiB
    unsigned short* hb   = (unsigned short*)(w + (64u << 20));      // 64 MiB
    float*          x1   = (float*)         (w + (128u << 20));     // 32 MiB
    unsigned short* Wqb  = (unsigned short*)(w + (160u << 20));     // 8 MiB
    unsigned short* Wkb  = (unsigned short*)(w + (168u << 20));     // 8 MiB
    unsigned short* Wvb  = (unsigned short*)(w + (176u << 20));     // 8 MiB
    unsigned short* Wob  = (unsigned short*)(w + (184u << 20));     // 8 MiB
    unsigned short* W1b  = (unsigned short*)(w + (192u << 20));     // 32 MiB
    unsigned short* W2b  = (unsigned short*)(w + (224u << 20));     // 32 MiB
    unsigned short* Pb   = (unsigned short*)(w + (256u << 20));     // 256 MiB bf16 probs
    unsigned short* Ohb   = xlnb;   // xln dead after QKV/Vt gemms
    unsigned short* xln2b = Kb;     // K dead after scores gemm

    const dim3 blk(256);
    const float one = 1.f;
    const float qk_scale = 0.08838834764831843f;   // 1/sqrt(128)
    const long Z4M = (long)SEQ * D_MODEL;          // 4,194,304
    const long ZSC = (long)SEQ * SEQ;              // 4,194,304
    const long ZOH = (long)SEQ * DHEAD;            // 262,144

    // 0) weights -> bf16 (every call; no persistent state allowed)
    const int nW = D_MODEL * D_MODEL / 4, nF = D_FF * D_MODEL / 4;
    hipLaunchKernelGGL(castbf_kernel, dim3(nW / 256), blk, 0, stream, Wq, Wqb, nW);
    hipLaunchKernelGGL(castbf_kernel, dim3(nW / 256), blk, 0, stream, Wk, Wkb, nW);
    hipLaunchKernelGGL(castbf_kernel, dim3(nW / 256), blk, 0, stream, Wv, Wvb, nW);
    hipLaunchKernelGGL(castbf_kernel, dim3(nW / 256), blk, 0, stream, Wo, Wob, nW);
    hipLaunchKernelGGL(castbf_kernel, dim3(nF / 256), blk, 0, stream, W1, W1b, nF);
    hipLaunchKernelGGL(castbf_kernel, dim3(nF / 256), blk, 0, stream, W2, W2b, nF);

    // 1) LN1 -> bf16
    hipLaunchKernelGGL(ln_kernel, dim3(ROWS), blk, 0, stream, x, ln1g, ln1b, xlnb);

    // 2) Q = xln@Wq^T+bq, K = xln@Wk^T+bk  (bf16 out)
    hipLaunchKernelGGL((gemm_mfma<true>), dim3(D_MODEL / 128, ROWS / 128, 1), blk, 0, stream,
                       xlnb, D_MODEL, Wqb, D_MODEL, bq, 0, nullptr, Qb, D_MODEL,
                       D_MODEL, one, 0, 0L, 0L, 0L, 0L, 0L, 0L, 1);
    hipLaunchKernelGGL((gemm_mfma<true>), dim3(D_MODEL / 128, ROWS / 128, 1), blk, 0, stream,
                       xlnb, D_MODEL, Wkb, D_MODEL, bk, 0, nullptr, Kb, D_MODEL,
                       D_MODEL, one, 0, 0L, 0L, 0L, 0L, 0L, 0L, 1);
    // 2c) V^T per batch: Vt[b][dout][s] = sum_k Wv[dout,k]*xln[b][s][k] + bv[dout]
    hipLaunchKernelGGL((gemm_mfma<true>), dim3(SEQ / 128, D_MODEL / 128, BATCH), blk, 0, stream,
                       Wvb, D_MODEL, xlnb, D_MODEL, bv, 1, nullptr, Vtb, SEQ,
                       D_MODEL, one, 0, 0L, 0L, Z4M, 0L, Z4M, 0L, 1);

    // 3) scores = Q_h @ K_h^T * qk_scale  (fp32, into d_out score region)
    hipLaunchKernelGGL((gemm_mfma<false>), dim3(SEQ / 128, SEQ / 128, BATCH * NHEADS), blk, 0, stream,
                       Qb, D_MODEL, Kb, D_MODEL, nullptr, 0, nullptr, out_score, SEQ,
                       DHEAD, qk_scale, 0,
                       Z4M, (long)DHEAD, Z4M, (long)DHEAD, (long)NHEADS * ZSC, ZSC, NHEADS);

    // 4) softmax in place (fp32) + bf16 P copy for PV
    hipLaunchKernelGGL(softmax_kernel, dim3(BATCH * NHEADS * SEQ), blk, 0, stream, out_score, Pb);

    // 5) Oh[b][h][s][d] = P @ V_h   (A = bf16 P, fast gload_lds path)
    hipLaunchKernelGGL((gemm_mfma<true>), dim3(DHEAD / 128, SEQ / 128, BATCH * NHEADS), blk, 0, stream,
                       Pb, SEQ, Vtb, SEQ, nullptr, 0, nullptr, Ohb, DHEAD,
                       SEQ, one, 0,
                       (long)NHEADS * ZSC, ZSC, Z4M, (long)DHEAD * SEQ,
                       (long)NHEADS * ZOH, ZOH, NHEADS);

    // 6) x1 = x + Oh_flat @ Wo^T + bo   (fp32 out)
    hipLaunchKernelGGL((gemm_mfma<false>), dim3(D_MODEL / 128, ROWS / 128, 1), blk, 0, stream,
                       Ohb, D_MODEL, Wob, D_MODEL, bo, 0, x, x1, D_MODEL,
                       D_MODEL, one, 0, 0L, 0L, 0L, 0L, 0L, 0L, 1);

    // 7) LN2 -> bf16
    hipLaunchKernelGGL(ln_kernel, dim3(ROWS), blk, 0, stream, x1, ln2g, ln2b, xln2b);

    // 8) h = relu(xln2 @ W1^T + b1)  (bf16 out)
    hipLaunchKernelGGL((gemm_mfma<true>), dim3(D_FF / 128, ROWS / 128, 1), blk, 0, stream,
                       xln2b, D_MODEL, W1b, D_MODEL, b1, 0, nullptr, hb, D_FF,
                       D_MODEL, one, 1, 0L, 0L, 0L, 0L, 0L, 0L, 1);

    // 9) out = x1 + h @ W2^T + b2  (fp32 out into d_out)
    hipLaunchKernelGGL((gemm_mfma<false>), dim3(D_MODEL / 128, ROWS / 128, 1), blk, 0, stream,
                       hb, D_FF, W2b, D_FF, b2, 0, x1, out_x, D_MODEL,
                       D_FF, one, 0, 0L, 0L, 0L, 0L, 0L, 0L, 1);
}

// Round 6
// 1837.541 us; speedup vs baseline: 1.0916x; 1.0717x over previous
//
#include <hip/hip_runtime.h>
#include <math.h>

#define D_MODEL 2048
#define NHEADS  16
#define DHEAD   128
#define SEQ     2048
#define BATCH   2
#define ROWS    (BATCH * SEQ)        // 4096
#define D_FF    (4 * D_MODEL)        // 8192

typedef __attribute__((ext_vector_type(8))) short bf16x8;   // 8 bf16 in 4 VGPRs
typedef __attribute__((ext_vector_type(4))) float f32x4;

// round-to-nearest-even fp32 -> bf16 (bit pattern)
__device__ __forceinline__ unsigned short f2bf(float f) {
    unsigned int u = __float_as_uint(f);
    u += 0x7fffu + ((u >> 16) & 1u);
    return (unsigned short)(u >> 16);
}

// ---------------- block reduce (sum or max) over 256 threads ----------------
__device__ __forceinline__ float block_reduce(float v, int is_max) {
    __shared__ float tmp[4];
    #pragma unroll
    for (int o = 32; o > 0; o >>= 1) {
        float other = __shfl_down(v, o, 64);
        v = is_max ? fmaxf(v, other) : (v + other);
    }
    __syncthreads();
    if ((threadIdx.x & 63) == 0) tmp[threadIdx.x >> 6] = v;
    __syncthreads();
    float r = is_max ? fmaxf(fmaxf(tmp[0], tmp[1]), fmaxf(tmp[2], tmp[3]))
                     : (tmp[0] + tmp[1] + tmp[2] + tmp[3]);
    return r;
}

// ---------------- fp32 -> bf16 cast (n4 = n/4 float4 groups) ----------------
__global__ __launch_bounds__(256)
void castbf_kernel(const float* __restrict__ in, unsigned short* __restrict__ out, int n4)
{
    int i = blockIdx.x * 256 + threadIdx.x;
    if (i < n4) {
        float4 v = ((const float4*)in)[i];
        ushort4 o;
        o.x = f2bf(v.x); o.y = f2bf(v.y); o.z = f2bf(v.z); o.w = f2bf(v.w);
        ((ushort4*)out)[i] = o;
    }
}

// ---------------- LayerNorm: fp32 in, bf16 out ------------------------------
__global__ __launch_bounds__(256)
void ln_kernel(const float* __restrict__ x, const float* __restrict__ g,
               const float* __restrict__ b, unsigned short* __restrict__ y)
{
    __shared__ float row[D_MODEL];
    const long r = blockIdx.x;
    const float4* xr = (const float4*)(x + r * D_MODEL);
    float s = 0.f;
    for (int i = threadIdx.x; i < D_MODEL / 4; i += 256) {
        float4 v = xr[i];
        ((float4*)row)[i] = v;
        s += v.x + v.y + v.z + v.w;
    }
    s = block_reduce(s, 0);
    const float mean = s * (1.f / D_MODEL);
    float vs = 0.f;
    for (int i = threadIdx.x; i < D_MODEL / 4; i += 256) {
        float4 v = ((const float4*)row)[i];
        float dx = v.x - mean; vs += dx * dx;
        dx = v.y - mean; vs += dx * dx;
        dx = v.z - mean; vs += dx * dx;
        dx = v.w - mean; vs += dx * dx;
    }
    vs = block_reduce(vs, 0);
    const float inv = rsqrtf(vs * (1.f / D_MODEL) + 1e-5f);
    const float4* g4 = (const float4*)g;
    const float4* b4 = (const float4*)b;
    for (int i = threadIdx.x; i < D_MODEL / 4; i += 256) {
        float4 v = ((const float4*)row)[i];
        float4 gg = g4[i], bb = b4[i];
        ushort4 o;
        o.x = f2bf((v.x - mean) * inv * gg.x + bb.x);
        o.y = f2bf((v.y - mean) * inv * gg.y + bb.y);
        o.z = f2bf((v.z - mean) * inv * gg.z + bb.z);
        o.w = f2bf((v.w - mean) * inv * gg.w + bb.w);
        *(ushort4*)(y + r * D_MODEL + i * 4) = o;
    }
}

// ---------------- Softmax in place + bf16 copy: one block per row -----------
__global__ __launch_bounds__(256)
void softmax_kernel(float* __restrict__ sc, unsigned short* __restrict__ pb)
{
    __shared__ float row[SEQ];
    float* p = sc + (long)blockIdx.x * SEQ;
    unsigned short* pbf = pb + (long)blockIdx.x * SEQ;
    float m = -1e30f;
    for (int i = threadIdx.x; i < SEQ / 4; i += 256) {
        float4 v = ((const float4*)p)[i];
        ((float4*)row)[i] = v;
        m = fmaxf(m, fmaxf(fmaxf(v.x, v.y), fmaxf(v.z, v.w)));
    }
    m = block_reduce(m, 1);
    float sum = 0.f;
    for (int i = threadIdx.x; i < SEQ; i += 256) {
        float e = expf(row[i] - m);
        row[i] = e;
        sum += e;
    }
    sum = block_reduce(sum, 0);
    const float inv = 1.f / sum;
    for (int i = threadIdx.x; i < SEQ / 4; i += 256) {
        float4 v = ((const float4*)row)[i];
        v.x *= inv; v.y *= inv; v.z *= inv; v.w *= inv;
        ((float4*)p)[i] = v;
        ushort4 o;
        o.x = f2bf(v.x); o.y = f2bf(v.y); o.z = f2bf(v.z); o.w = f2bf(v.w);
        ((ushort4*)pbf)[i] = o;
    }
}

// ---------------- MFMA bf16 GEMM --------------------------------------------
// C[m,n] = relu?( scale * sum_k A[m,k]*B[n,k] + bias + resid[m,n] )
// A,B: bf16 [M,K]/[N,K]. Batched over blockIdx.z. Tile 128x128, BK=64, 4 waves.
// DBUF=true : 2-phase double-buffer (T3-minimum recipe): stage next tile,
//             compute current, ONE counted drain + raw s_barrier per K-step.
//             64 KB dynamic LDS -> 2 blocks/CU (matches our low-occupancy grids).
// DBUF=false: m97-style single buffer (for grids >= 3 blocks/CU), 32 KB LDS.
// Epilogue: acc -> swizzled LDS -> coalesced stores (proven R5).
// Requires M%128==0, N%128==0, K%64==0.
constexpr int BK = 64;

// direct global->LDS DMA, linear [128][64] bf16 layout.
// Wave w covers rows [w*32, w*32+32): 4 issues of 8 rows (1 KB each).
__device__ __forceinline__ void stage_lds(const unsigned short* gbase, int ld,
                                          unsigned short* lds, int wid, int lane)
{
    const int l8 = lane >> 3, c8 = lane & 7;
    #pragma unroll
    for (int i = 0; i < 4; ++i) {
        const int rowb = wid * 32 + i * 8;
        const unsigned short* src = gbase + (size_t)(rowb + l8) * ld + c8 * 8;
        unsigned short* dst = lds + rowb * 64;
        __builtin_amdgcn_global_load_lds(
            (const __attribute__((address_space(1))) unsigned int*)src,
            (__attribute__((address_space(3))) unsigned int*)dst, 16, 0, 0);
    }
}

template<bool OUTBF, bool DBUF>
__global__ __launch_bounds__(256)
void gemm_mfma(const unsigned short* __restrict__ A, int lda,
               const unsigned short* __restrict__ B, int ldb,
               const float* __restrict__ bias, int biasM,
               const float* __restrict__ resid,
               void* __restrict__ Cv, int ldc,
               int Kdim, float scale, int relu,
               long sAb, long sAh, long sBb, long sBh, long sCb, long sCh,
               int nh)
{
    extern __shared__ char smem[];           // 32 KB (single) / 64 KB (dbuf)

    const int z  = blockIdx.z;
    const int zb = z / nh, zh = z % nh;
    A += zb * sAb + zh * sAh;
    B += zb * sBb + zh * sBh;
    const long coff = zb * sCb + zh * sCh;
    float*          Cf = (float*)Cv + coff;
    unsigned short* Ch = (unsigned short*)Cv + coff;

    const int bm = blockIdx.y * 128;
    const int bn = blockIdx.x * 128;
    const int t  = threadIdx.x;
    const int lane = t & 63;
    const int wid  = t >> 6;
    const int wr = wid >> 1, wc = wid & 1;     // wave -> 64x64 sub-tile
    const int li = lane & 15;
    const int g  = lane >> 4;                  // k-group 0..3

    f32x4 acc[4][4];
    #pragma unroll
    for (int i = 0; i < 4; ++i)
        #pragma unroll
        for (int j = 0; j < 4; ++j) acc[i][j] = (f32x4){0.f, 0.f, 0.f, 0.f};

    int aoffs[4], boffs[4];
    #pragma unroll
    for (int m = 0; m < 4; ++m) {
        const int ra = wr * 64 + m * 16 + li;
        const int rb = wc * 64 + m * 16 + li;
        aoffs[m] = ra * 128 + (g << 4);        // bits >= 7 | bits 4-5 (bit 6 free)
        boffs[m] = rb * 128 + (g << 4);
    }

    // compute one BK=64 tile from LDS pair (AsB, BsB = byte pointers)
    auto compute_tile = [&](const char* AsB, const char* BsB) {
        #pragma unroll
        for (int kk = 0; kk < 2; ++kk) {       // two K=32 MFMA slabs
            const int kb = kk * 64;            // toggles bit 6 only
            bf16x8 a[4], b[4];
            #pragma unroll
            for (int m = 0; m < 4; ++m) {
                a[m] = *(const bf16x8*)(AsB + (aoffs[m] ^ kb));
                b[m] = *(const bf16x8*)(BsB + (boffs[m] ^ kb));
            }
            #pragma unroll
            for (int m = 0; m < 4; ++m)
                #pragma unroll
                for (int n = 0; n < 4; ++n)
                    acc[m][n] = __builtin_amdgcn_mfma_f32_16x16x32_bf16(
                                    a[m], b[n], acc[m][n], 0, 0, 0);
        }
    };

    const unsigned short* Abase = A + (size_t)bm * lda;
    const unsigned short* Bbase = B + (size_t)bn * ldb;

    if (DBUF) {
        // ---- 2-phase double buffer; raw barriers, one drain per K-step ----
        stage_lds(Abase, lda, (unsigned short*)smem,           wid, lane);
        stage_lds(Bbase, ldb, (unsigned short*)(smem + 16384), wid, lane);
        asm volatile("s_waitcnt vmcnt(0)" ::: "memory");
        __builtin_amdgcn_s_barrier();
        int cur = 0;
        for (int k0 = 0; k0 < Kdim; k0 += BK) {
            const bool more = (k0 + BK < Kdim);          // wave-uniform
            char* nxt = smem + (cur ^ 1) * 32768;
            if (more) {
                stage_lds(Abase + k0 + BK, lda, (unsigned short*)nxt,           wid, lane);
                stage_lds(Bbase + k0 + BK, ldb, (unsigned short*)(nxt + 16384), wid, lane);
            }
            const char* curb = smem + cur * 32768;
            compute_tile(curb, curb + 16384);            // overlaps next-tile loads
            if (more) {
                asm volatile("s_waitcnt vmcnt(0)" ::: "memory");
                __builtin_amdgcn_s_barrier();
                cur ^= 1;
            }
        }
    } else {
        // ---- m97-style single buffer (high-occupancy launches) ----
        for (int k0 = 0; k0 < Kdim; k0 += BK) {
            stage_lds(Abase + k0, lda, (unsigned short*)smem,           wid, lane);
            stage_lds(Bbase + k0, ldb, (unsigned short*)(smem + 16384), wid, lane);
            __syncthreads();
            compute_tile(smem, smem + 16384);
            __syncthreads();
        }
    }

    // ---- epilogue via LDS roundtrip: 2 passes of 64 rows x 128 cols fp32 ----
    // MFMA C layout: col = lane&15, row = (lane>>4)*4 + reg  [HW-verified].
    float* epi = (float*)smem;
    const int g4 = g * 4;
    const int lrow_r = t >> 2, q = t & 3;      // readback mapping
    #pragma unroll
    for (int p = 0; p < 2; ++p) {
        __syncthreads();
        #pragma unroll
        for (int mm = 0; mm < 2; ++mm) {
            const int m = 2 * p + mm;
            #pragma unroll
            for (int n = 0; n < 4; ++n) {
                const int col = wc * 64 + n * 16 + li;
                #pragma unroll
                for (int r = 0; r < 4; ++r) {
                    const int lrow = wr * 32 + mm * 16 + g4 + r;
                    const int byteoff = lrow * 512 + ((((col >> 2) ^ (lrow & 7)) << 4)) + (col & 3) * 4;
                    *(float*)((char*)epi + byteoff) = acc[m][n][r];
                }
            }
        }
        __syncthreads();
        const long grow = bm + (lrow_r >> 5) * 64 + p * 32 + (lrow_r & 31);
        const int col0 = bn + q * 32;
        float v[32];
        #pragma unroll
        for (int i = 0; i < 8; ++i) {
            const int byteoff = lrow_r * 512 + ((((q * 8 + i) ^ (lrow_r & 7)) << 4));
            *(f32x4*)&v[i * 4] = *(const f32x4*)((const char*)epi + byteoff);
        }
        #pragma unroll
        for (int i = 0; i < 32; ++i) v[i] *= scale;
        if (bias) {
            if (biasM) {
                const float bm_ = bias[grow];
                #pragma unroll
                for (int i = 0; i < 32; ++i) v[i] += bm_;
            } else {
                #pragma unroll
                for (int i = 0; i < 8; ++i) {
                    f32x4 bb = *(const f32x4*)(bias + col0 + i * 4);
                    v[i * 4 + 0] += bb[0]; v[i * 4 + 1] += bb[1];
                    v[i * 4 + 2] += bb[2]; v[i * 4 + 3] += bb[3];
                }
            }
        }
        if (resid) {
            const float* rr = resid + grow * (long)ldc + col0;
            #pragma unroll
            for (int i = 0; i < 8; ++i) {
                f32x4 r4 = *(const f32x4*)(rr + i * 4);
                v[i * 4 + 0] += r4[0]; v[i * 4 + 1] += r4[1];
                v[i * 4 + 2] += r4[2]; v[i * 4 + 3] += r4[3];
            }
        }
        if (relu) {
            #pragma unroll
            for (int i = 0; i < 32; ++i) v[i] = fmaxf(v[i], 0.f);
        }
        if (OUTBF) {
            unsigned short* cp = Ch + grow * (long)ldc + col0;
            #pragma unroll
            for (int i = 0; i < 4; ++i) {
                bf16x8 o;
                #pragma unroll
                for (int j = 0; j < 8; ++j) o[j] = (short)f2bf(v[i * 8 + j]);
                *(bf16x8*)(cp + i * 8) = o;
            }
        } else {
            float* cp = Cf + grow * (long)ldc + col0;
            #pragma unroll
            for (int i = 0; i < 8; ++i)
                *(f32x4*)(cp + i * 4) = *(const f32x4*)&v[i * 4];
        }
    }
}

// ---------------------------------------------------------------------------
extern "C" void kernel_launch(void* const* d_in, const int* in_sizes, int n_in,
                              void* d_out, int out_size, void* d_ws, size_t ws_size,
                              hipStream_t stream)
{
    const float* x    = (const float*)d_in[0];
    const float* Wq   = (const float*)d_in[1];
    const float* bq   = (const float*)d_in[2];
    const float* Wk   = (const float*)d_in[3];
    const float* bk   = (const float*)d_in[4];
    const float* Wv   = (const float*)d_in[5];
    const float* bv   = (const float*)d_in[6];
    const float* Wo   = (const float*)d_in[7];
    const float* bo   = (const float*)d_in[8];
    const float* ln1g = (const float*)d_in[9];
    const float* ln1b = (const float*)d_in[10];
    const float* W1   = (const float*)d_in[11];
    const float* b1   = (const float*)d_in[12];
    const float* W2   = (const float*)d_in[13];
    const float* b2   = (const float*)d_in[14];
    const float* ln2g = (const float*)d_in[15];
    const float* ln2b = (const float*)d_in[16];

    const long XN = (long)ROWS * D_MODEL;      // 8,388,608
    float* out_x     = (float*)d_out;
    float* out_score = out_x + XN;             // [2][16][2048][2048] fp32

    // ---- workspace carve-up (bytes; 512 MiB used, d_ws is ~2.2 GiB) ----
    char* w = (char*)d_ws;
    unsigned short* Qb   = (unsigned short*)(w);                    // 16 MiB
    unsigned short* Kb   = (unsigned short*)(w + (16u << 20));      // 16 MiB
    unsigned short* Vtb  = (unsigned short*)(w + (32u << 20));      // 16 MiB
    unsigned short* xlnb = (unsigned short*)(w + (48u << 20));      // 16 MiB
    unsigned short* hb   = (unsigned short*)(w + (64u << 20));      // 64 MiB
    float*          x1   = (float*)         (w + (128u << 20));     // 32 MiB
    unsigned short* Wqb  = (unsigned short*)(w + (160u << 20));     // 8 MiB
    unsigned short* Wkb  = (unsigned short*)(w + (168u << 20));     // 8 MiB
    unsigned short* Wvb  = (unsigned short*)(w + (176u << 20));     // 8 MiB
    unsigned short* Wob  = (unsigned short*)(w + (184u << 20));     // 8 MiB
    unsigned short* W1b  = (unsigned short*)(w + (192u << 20));     // 32 MiB
    unsigned short* W2b  = (unsigned short*)(w + (224u << 20));     // 32 MiB
    unsigned short* Pb   = (unsigned short*)(w + (256u << 20));     // 256 MiB bf16 probs
    unsigned short* Ohb   = xlnb;   // xln dead after QKV/Vt gemms
    unsigned short* xln2b = Kb;     // K dead after scores gemm

    const dim3 blk(256);
    const float one = 1.f;
    const float qk_scale = 0.08838834764831843f;   // 1/sqrt(128)
    const long Z4M = (long)SEQ * D_MODEL;          // 4,194,304
    const long ZSC = (long)SEQ * SEQ;              // 4,194,304
    const long ZOH = (long)SEQ * DHEAD;            // 262,144
    const unsigned LDS1 = 32768, LDS2 = 65536;

    // 0) weights -> bf16 (every call; no persistent state allowed)
    const int nW = D_MODEL * D_MODEL / 4, nF = D_FF * D_MODEL / 4;
    hipLaunchKernelGGL(castbf_kernel, dim3(nW / 256), blk, 0, stream, Wq, Wqb, nW);
    hipLaunchKernelGGL(castbf_kernel, dim3(nW / 256), blk, 0, stream, Wk, Wkb, nW);
    hipLaunchKernelGGL(castbf_kernel, dim3(nW / 256), blk, 0, stream, Wv, Wvb, nW);
    hipLaunchKernelGGL(castbf_kernel, dim3(nW / 256), blk, 0, stream, Wo, Wob, nW);
    hipLaunchKernelGGL(castbf_kernel, dim3(nF / 256), blk, 0, stream, W1, W1b, nF);
    hipLaunchKernelGGL(castbf_kernel, dim3(nF / 256), blk, 0, stream, W2, W2b, nF);

    // 1) LN1 -> bf16
    hipLaunchKernelGGL(ln_kernel, dim3(ROWS), blk, 0, stream, x, ln1g, ln1b, xlnb);

    // 2) Q, K projections (bf16 out) — 512 blocks = 2/CU -> DBUF
    hipLaunchKernelGGL((gemm_mfma<true, true>), dim3(D_MODEL / 128, ROWS / 128, 1), blk, LDS2, stream,
                       xlnb, D_MODEL, Wqb, D_MODEL, bq, 0, nullptr, Qb, D_MODEL,
                       D_MODEL, one, 0, 0L, 0L, 0L, 0L, 0L, 0L, 1);
    hipLaunchKernelGGL((gemm_mfma<true, true>), dim3(D_MODEL / 128, ROWS / 128, 1), blk, LDS2, stream,
                       xlnb, D_MODEL, Wkb, D_MODEL, bk, 0, nullptr, Kb, D_MODEL,
                       D_MODEL, one, 0, 0L, 0L, 0L, 0L, 0L, 0L, 1);
    // 2c) V^T per batch: Vt[b][dout][s], bias along M — 512 blocks -> DBUF
    hipLaunchKernelGGL((gemm_mfma<true, true>), dim3(SEQ / 128, D_MODEL / 128, BATCH), blk, LDS2, stream,
                       Wvb, D_MODEL, xlnb, D_MODEL, bv, 1, nullptr, Vtb, SEQ,
                       D_MODEL, one, 0, 0L, 0L, Z4M, 0L, Z4M, 0L, 1);

    // 3) scores = Q_h @ K_h^T * qk_scale — 8192 blocks = 32/CU -> single buffer
    hipLaunchKernelGGL((gemm_mfma<false, false>), dim3(SEQ / 128, SEQ / 128, BATCH * NHEADS), blk, LDS1, stream,
                       Qb, D_MODEL, Kb, D_MODEL, nullptr, 0, nullptr, out_score, SEQ,
                       DHEAD, qk_scale, 0,
                       Z4M, (long)DHEAD, Z4M, (long)DHEAD, (long)NHEADS * ZSC, ZSC, NHEADS);

    // 4) softmax in place (fp32) + bf16 P copy for PV
    hipLaunchKernelGGL(softmax_kernel, dim3(BATCH * NHEADS * SEQ), blk, 0, stream, out_score, Pb);

    // 5) Oh = P @ V_h — 512 blocks -> DBUF
    hipLaunchKernelGGL((gemm_mfma<true, true>), dim3(DHEAD / 128, SEQ / 128, BATCH * NHEADS), blk, LDS2, stream,
                       Pb, SEQ, Vtb, SEQ, nullptr, 0, nullptr, Ohb, DHEAD,
                       SEQ, one, 0,
                       (long)NHEADS * ZSC, ZSC, Z4M, (long)DHEAD * SEQ,
                       (long)NHEADS * ZOH, ZOH, NHEADS);

    // 6) x1 = x + Oh_flat @ Wo^T + bo — 512 blocks -> DBUF
    hipLaunchKernelGGL((gemm_mfma<false, true>), dim3(D_MODEL / 128, ROWS / 128, 1), blk, LDS2, stream,
                       Ohb, D_MODEL, Wob, D_MODEL, bo, 0, x, x1, D_MODEL,
                       D_MODEL, one, 0, 0L, 0L, 0L, 0L, 0L, 0L, 1);

    // 7) LN2 -> bf16
    hipLaunchKernelGGL(ln_kernel, dim3(ROWS), blk, 0, stream, x1, ln2g, ln2b, xln2b);

    // 8) h = relu(xln2 @ W1^T + b1) — 2048 blocks = 8/CU -> single buffer
    hipLaunchKernelGGL((gemm_mfma<true, false>), dim3(D_FF / 128, ROWS / 128, 1), blk, LDS1, stream,
                       xln2b, D_MODEL, W1b, D_MODEL, b1, 0, nullptr, hb, D_FF,
                       D_MODEL, one, 1, 0L, 0L, 0L, 0L, 0L, 0L, 1);

    // 9) out = x1 + h @ W2^T + b2 — 512 blocks -> DBUF
    hipLaunchKernelGGL((gemm_mfma<false, true>), dim3(D_MODEL / 128, ROWS / 128, 1), blk, LDS2, stream,
                       hb, D_FF, W2b, D_FF, b2, 0, x1, out_x, D_MODEL,
                       D_FF, one, 0, 0L, 0L, 0L, 0L, 0L, 0L, 1);
}